// Round 8
// baseline (241.084 us; speedup 1.0000x reference)
//
#include <hip/hip_runtime.h>
#include <hip/hip_bf16.h>

#define EPSV 1e-5f
typedef __hip_bfloat16 bf16;
typedef __attribute__((ext_vector_type(8))) short v8s;
typedef __attribute__((ext_vector_type(4))) float v4f;
__device__ __forceinline__ float b2f(bf16 v) { return __bfloat162float(v); }
__device__ __forceinline__ bf16 f2b(float v) { return __float2bfloat16(v); }
__device__ __forceinline__ float bs2f(short s) {
  return __uint_as_float(((unsigned)(unsigned short)s) << 16);
}

__global__ __launch_bounds__(256) void fill_k(float* __restrict__ out, float val, int n)
{
  int i = blockIdx.x * 256 + threadIdx.x;
  if (i < n) out[i] = val;
}

// ---------- prep: pack conv2/conv3 weights [(s)*32+ic][oc] bf16; We->bf16; WebT[e][h][d] ----------
__global__ __launch_bounds__(256) void prep_w_k(
    const float* __restrict__ w2, const float* __restrict__ w3,
    const float* __restrict__ We,
    bf16* __restrict__ w2b, bf16* __restrict__ w3b,
    bf16* __restrict__ Web, bf16* __restrict__ WebT)
{
  int i = blockIdx.x * 256 + threadIdx.x;
  if (i < 9216) {
    int oc = i & 31, k = i >> 5, s = k >> 5, ic = k & 31;
    w2b[i] = f2b(w2[oc * 288 + ic * 9 + s]);
  } else if (i < 18432) {
    int j = i - 9216;
    int oc = j & 31, k = j >> 5, s = k >> 5, ic = k & 31;
    w3b[j] = f2b(w3[oc * 288 + ic * 9 + s]);
  } else if (i < 18432 + 49152) {
    int j = i - 18432;
    Web[j] = f2b(We[j]);
  } else if (i < 18432 + 98304) {
    int j = i - 18432 - 49152;               // j = e*16384 + h*128 + d
    int e = j >> 14, r = j & 16383, h = r >> 7, d = r & 127;
    WebT[j] = f2b(We[e * 16384 + d * 128 + h]);
  }
}

// ---------- conv1 stats via autocorrelation: 4 images/block -> 54 partials ----------
__global__ __launch_bounds__(256) void conv1_acc_k(
    const float* __restrict__ x, float* __restrict__ partial)
{
  int t = threadIdx.x;
  __shared__ __align__(16) float xs[1024];
  float M[45], S[9];
#pragma unroll
  for (int k = 0; k < 45; ++k) M[k] = 0.f;
#pragma unroll
  for (int k = 0; k < 9; ++k) S[k] = 0.f;
  for (int im = 0; im < 4; ++im) {
    int img = blockIdx.x * 4 + im;
    ((float4*)xs)[t] = ((const float4*)(x + img * 1024))[t];
    __syncthreads();
    for (int p = t; p < 900; p += 256) {
      int y = p / 30, xx = p - y * 30;
      const float* r0 = xs + y * 32 + xx;
      float v[9];
      v[0] = r0[0];  v[1] = r0[1];  v[2] = r0[2];
      v[3] = r0[32]; v[4] = r0[33]; v[5] = r0[34];
      v[6] = r0[64]; v[7] = r0[65]; v[8] = r0[66];
      int idx = 0;
#pragma unroll
      for (int i = 0; i < 9; ++i) {
        S[i] += v[i];
#pragma unroll
        for (int j = i; j < 9; ++j) M[idx++] = fmaf(v[i], v[j], M[idx]);
      }
    }
    __syncthreads();
  }
  // wave reduce all 54
  float a[54];
#pragma unroll
  for (int k = 0; k < 45; ++k) a[k] = M[k];
#pragma unroll
  for (int k = 0; k < 9; ++k) a[45 + k] = S[k];
#pragma unroll
  for (int k = 0; k < 54; ++k) {
#pragma unroll
    for (int off = 32; off; off >>= 1) a[k] += __shfl_down(a[k], off, 64);
  }
  __shared__ float red[4][54];
  int wv = t >> 6, lane = t & 63;
  if (lane == 0) {
#pragma unroll
    for (int k = 0; k < 54; ++k) red[wv][k] = a[k];
  }
  __syncthreads();
  if (t < 54)
    partial[blockIdx.x * 64 + t] = red[0][t] + red[1][t] + red[2][t] + red[3][t];
}

// ---------- reduce 512 blocks of 54 partials ----------
__global__ __launch_bounds__(256) void reduce54_k(
    const float* __restrict__ partial, float* __restrict__ Mred)
{
  int c = blockIdx.x, t = threadIdx.x;
  float s = 0.f;
  for (int i = t; i < 512; i += 256) s += partial[i * 64 + c];
#pragma unroll
  for (int off = 32; off; off >>= 1) s += __shfl_down(s, off, 64);
  __shared__ float rs[4];
  int wv = t >> 6, lane = t & 63;
  if (lane == 0) rs[wv] = s;
  __syncthreads();
  if (t == 0) Mred[c] = rs[0] + rs[1] + rs[2] + rs[3];
}

// ---------- conv1 BN params from autocorrelation ----------
__global__ void bn1_final_k(
    const float* __restrict__ Mred, const float* __restrict__ w1,
    const float* __restrict__ b1, const float* __restrict__ g,
    const float* __restrict__ bt, float* __restrict__ bnp)
{
  __shared__ float Ms[54];
  int t = threadIdx.x;
  if (t < 54) Ms[t] = Mred[t];
  __syncthreads();
  if (t < 32) {
    float w[9];
#pragma unroll
    for (int j = 0; j < 9; ++j) w[j] = w1[t * 9 + j];
    float b = b1[t];
    float wS = 0.f;
#pragma unroll
    for (int i = 0; i < 9; ++i) wS = fmaf(w[i], Ms[45 + i], wS);
    float wMw = 0.f;
    int idx = 0;
#pragma unroll
    for (int i = 0; i < 9; ++i)
#pragma unroll
      for (int j = i; j < 9; ++j) {
        float coef = (i == j) ? 1.f : 2.f;
        wMw = fmaf(coef * w[i] * w[j], Ms[idx++], wMw);
      }
    const float Np = 2048.f * 900.f;
    float mean = (wS + Np * b) / Np;
    float sumsq = wMw + 2.f * b * wS + Np * b * b;
    float var = sumsq / Np - mean * mean;
    float sc = g[t] / sqrtf(var + EPSV);
    bnp[2 * t] = sc;
    bnp[2 * t + 1] = bt[t] - mean * sc;
  }
}

// ---------- conv1 apply: block per image, float2 patch loads, regs for weights ----------
__global__ __launch_bounds__(256) void conv1_apply_k(
    const float* __restrict__ x, const float* __restrict__ w1,
    const float* __restrict__ b1, const float* __restrict__ bnp,
    bf16* __restrict__ pooled1)
{
  int img = blockIdx.x, t = threadIdx.x;
  __shared__ __align__(16) float xs[1024];
  ((float4*)xs)[t] = ((const float4*)(x + img * 1024))[t];
  __syncthreads();
  int c = t & 31;                            // constant per thread across loop
  float w[9];
#pragma unroll
  for (int j = 0; j < 9; ++j) w[j] = w1[c * 9 + j];
  float bias = b1[c], sc = bnp[2 * c], sh = bnp[2 * c + 1];
  bf16* outp = pooled1 + img * 7200;
  for (int idx = t; idx < 7200; idx += 256) {
    int pp = idx >> 5;
    int py = pp / 15, px = pp - py * 15;
    int y0 = 2 * py, x0 = 2 * px;
    float rv[4][4];
#pragma unroll
    for (int rr = 0; rr < 4; ++rr) {
      float2 lo = *(const float2*)(xs + (y0 + rr) * 32 + x0);
      float2 hi = *(const float2*)(xs + (y0 + rr) * 32 + x0 + 2);
      rv[rr][0] = lo.x; rv[rr][1] = lo.y; rv[rr][2] = hi.x; rv[rr][3] = hi.y;
    }
    float r = 0.f;
#pragma unroll
    for (int i = 0; i < 2; ++i)
#pragma unroll
      for (int j = 0; j < 2; ++j) {
        float v = bias;
        v = fmaf(rv[i][j],     w[0], v); v = fmaf(rv[i][j + 1],     w[1], v); v = fmaf(rv[i][j + 2],     w[2], v);
        v = fmaf(rv[i + 1][j], w[3], v); v = fmaf(rv[i + 1][j + 1], w[4], v); v = fmaf(rv[i + 1][j + 2], w[5], v);
        v = fmaf(rv[i + 2][j], w[6], v); v = fmaf(rv[i + 2][j + 1], w[7], v); v = fmaf(rv[i + 2][j + 2], w[8], v);
        r += fmaxf(fmaf(v, sc, sh), 0.f);
      }
    outp[idx] = f2b(r * 0.25f);
  }
}

// ---------- generic partial reduce -> scale/shift (conv2/conv3 stats) ----------
__global__ __launch_bounds__(256) void bn_reduce_partial_k(
    const float* __restrict__ partial, const float* __restrict__ g,
    const float* __restrict__ bt, float* __restrict__ bnp,
    int nimg, float invn)
{
  int c = blockIdx.x, t = threadIdx.x;
  float s = 0.f, ss = 0.f;
  for (int i = t; i < nimg; i += 256) {
    s += partial[i * 64 + c * 2];
    ss += partial[i * 64 + c * 2 + 1];
  }
#pragma unroll
  for (int off = 32; off; off >>= 1) { s += __shfl_down(s, off, 64); ss += __shfl_down(ss, off, 64); }
  __shared__ float rs[4], rss[4];
  int wv = t >> 6, lane = t & 63;
  if (lane == 0) { rs[wv] = s; rss[wv] = ss; }
  __syncthreads();
  if (t == 0) {
    s = rs[0] + rs[1] + rs[2] + rs[3];
    ss = rss[0] + rss[1] + rss[2] + rss[3];
    float mean = s * invn;
    float var = ss * invn - mean * mean;
    float sc = g[c] / sqrtf(var + EPSV);
    bnp[2 * c] = sc;
    bnp[2 * c + 1] = bt[c] - mean * sc;
  }
}

// ---------- implicit-GEMM conv via MFMA, NHWC in/out, fused BN-stats partials ----------
template <int IN_W, int OUT_W, int OUT_PIX, bool OUT_BF16>
__global__ __launch_bounds__(256) void conv_mfma_k(
    const bf16* __restrict__ in, const bf16* __restrict__ wb,
    void* __restrict__ outv, float* __restrict__ partial, int ntiles)
{
  constexpr int IN_PIX = IN_W * IN_W;
  int t = threadIdx.x, lane = t & 63;
  int m = lane & 15, kg = lane >> 4;
  const short* wbs = (const short*)wb;
  v8s bfr[9][2];
#pragma unroll
  for (int s = 0; s < 9; ++s)
#pragma unroll
    for (int ob = 0; ob < 2; ++ob)
#pragma unroll
      for (int j = 0; j < 8; ++j)
        bfr[s][ob][j] = wbs[(s * 32 + kg * 8 + j) * 32 + ob * 16 + m];

  float rs0 = 0.f, rss0 = 0.f, rs1 = 0.f, rss1 = 0.f;
  int gwave = blockIdx.x * 4 + (t >> 6);
  int nw = gridDim.x * 4;
  for (int tile = gwave; tile < ntiles; tile += nw) {
    unsigned p = tile * 16 + m;
    unsigned img = p / OUT_PIX, pix = p - img * OUT_PIX;
    unsigned y = pix / OUT_W, x = pix - y * OUT_W;
    const bf16* ap = in + img * (IN_PIX * 32) + (y * IN_W + x) * 32 + kg * 8;
    v4f acc0 = {0.f, 0.f, 0.f, 0.f}, acc1 = {0.f, 0.f, 0.f, 0.f};
#pragma unroll
    for (int ky = 0; ky < 3; ++ky)
#pragma unroll
      for (int kx = 0; kx < 3; ++kx) {
        v8s a = *(const v8s*)(ap + (ky * IN_W + kx) * 32);
        acc0 = __builtin_amdgcn_mfma_f32_16x16x32_bf16(a, bfr[ky * 3 + kx][0], acc0, 0, 0, 0);
        acc1 = __builtin_amdgcn_mfma_f32_16x16x32_bf16(a, bfr[ky * 3 + kx][1], acc1, 0, 0, 0);
      }
#pragma unroll
    for (int j = 0; j < 4; ++j) {
      rs0 += acc0[j]; rss0 = fmaf(acc0[j], acc0[j], rss0);
      rs1 += acc1[j]; rss1 = fmaf(acc1[j], acc1[j], rss1);
      unsigned pr = tile * 16 + kg * 4 + j;          // C row = (lane>>4)*4 + reg
      unsigned img2 = pr / OUT_PIX, pix2 = pr - img2 * OUT_PIX;
      unsigned base = (img2 * OUT_PIX + pix2) * 32;  // NHWC
      if (OUT_BF16) {
        bf16* o = (bf16*)outv;
        o[base + m] = f2b(acc0[j]);
        o[base + 16 + m] = f2b(acc1[j]);
      } else {
        float* o = (float*)outv;
        o[base + m] = acc0[j];
        o[base + 16 + m] = acc1[j];
      }
    }
  }
  rs0 += __shfl_xor(rs0, 16, 64);  rs0 += __shfl_xor(rs0, 32, 64);
  rss0 += __shfl_xor(rss0, 16, 64); rss0 += __shfl_xor(rss0, 32, 64);
  rs1 += __shfl_xor(rs1, 16, 64);  rs1 += __shfl_xor(rs1, 32, 64);
  rss1 += __shfl_xor(rss1, 16, 64); rss1 += __shfl_xor(rss1, 32, 64);
  __shared__ float red[4][32][2];
  int wv = t >> 6;
  if (lane < 16) {
    red[wv][lane][0] = rs0;      red[wv][lane][1] = rss0;
    red[wv][16 + lane][0] = rs1; red[wv][16 + lane][1] = rss1;
  }
  __syncthreads();
  if (t < 64) {
    int cc = t >> 1, j = t & 1;
    partial[blockIdx.x * 64 + t] = red[0][cc][j] + red[1][cc][j] + red[2][cc][j] + red[3][cc][j];
  }
}

// ---------- conv2 apply: NHWC vectorized BN+ReLU+pool 13->6 -> NHWC bf16 ----------
__global__ __launch_bounds__(256) void conv2_apply_k(
    const bf16* __restrict__ in, const float* __restrict__ bnp,
    bf16* __restrict__ out)
{
  int idx = blockIdx.x * 256 + threadIdx.x;  // exactly 2048*36*4
  int img = idx / 144, r = idx - img * 144;
  int pp = r >> 2, c8 = r & 3;
  int py = pp / 6, px = pp - py * 6;
  int ip0 = (2 * py) * 13 + 2 * px;
  const bf16* bp = in + (img * 169 + ip0) * 32 + c8 * 8;
  v8s a = *(const v8s*)bp;
  v8s b = *(const v8s*)(bp + 32);
  v8s cc = *(const v8s*)(bp + 13 * 32);
  v8s d = *(const v8s*)(bp + 14 * 32);
  const float* bn = bnp + c8 * 16;
  union { v8s v; short s[8]; bf16 h[8]; } res;
#pragma unroll
  for (int k = 0; k < 8; ++k) {
    float sc = bn[2 * k], sh = bn[2 * k + 1];
    float v = fmaxf(fmaf(bs2f(a[k]), sc, sh), 0.f) + fmaxf(fmaf(bs2f(b[k]), sc, sh), 0.f)
            + fmaxf(fmaf(bs2f(cc[k]), sc, sh), 0.f) + fmaxf(fmaf(bs2f(d[k]), sc, sh), 0.f);
    res.h[k] = f2b(v * 0.25f);
  }
  *(v8s*)(out + (img * 36 + pp) * 32 + c8 * 8) = res.v;
}

// ---------- conv3 apply + pool + broadcast to 4 beams (NHWC fp32 in) ----------
__global__ __launch_bounds__(256) void conv3_apply_k(
    const float* __restrict__ in, const float* __restrict__ bnp,
    float* __restrict__ hs)
{
  int idx = blockIdx.x * 256 + threadIdx.x;  // exactly 2048*128
  int img = idx >> 7, r = idx & 127;
  int c = r >> 2, q = r & 3;
  int py = q >> 1, px = q & 1;
  int p0 = py * 8 + px * 2;
  const float* bp = in + img * 512 + c;
  float sc = bnp[2 * c], sh = bnp[2 * c + 1];
  float v = (fmaxf(fmaf(bp[p0 * 32], sc, sh), 0.f)
           + fmaxf(fmaf(bp[(p0 + 1) * 32], sc, sh), 0.f)
           + fmaxf(fmaf(bp[(p0 + 4) * 32], sc, sh), 0.f)
           + fmaxf(fmaf(bp[(p0 + 5) * 32], sc, sh), 0.f)) * 0.25f;
  float* hb = hs + img * 512 + r;
  hb[0] = v; hb[128] = v; hb[256] = v; hb[384] = v;
}

// ---------- MoE step: transposed bf16 weights, contiguous per-lane loads ----------
__global__ __launch_bounds__(256) void moe_naive_k(
    const float* __restrict__ hin, float* __restrict__ hout,
    const float* __restrict__ traj, const bf16* __restrict__ WebT,
    const float* __restrict__ be, int step)
{
  int gid = blockIdx.x * 256 + threadIdx.x;  // exactly 8192*128
  int row = gid >> 7, h = gid & 127;
  float4 tv = ((const float4*)traj)[step * 8192 + row];
  int e = 0; float bv = tv.x;
  if (tv.y > bv) { bv = tv.y; e = 1; }
  if (tv.z > bv) { bv = tv.z; e = 2; }
  if (tv.w > bv) { bv = tv.w; e = 3; }
  float v;
  if (e == 3) {
    v = hin[row * 128 + h];
  } else {
    const float* hr = hin + row * 128;       // wave-uniform row -> s_loads
    const bf16* wp = WebT + e * 16384 + h * 128;
    float a0 = be[e * 128 + h], a1 = 0.f, a2 = 0.f, a3 = 0.f;
#pragma unroll
    for (int d0 = 0; d0 < 128; d0 += 8) {
      v8s wv = *(const v8s*)(wp + d0);
      float4 h0 = *(const float4*)(hr + d0);
      float4 h1 = *(const float4*)(hr + d0 + 4);
      a0 = fmaf(h0.x, bs2f(wv[0]), a0);
      a1 = fmaf(h0.y, bs2f(wv[1]), a1);
      a2 = fmaf(h0.z, bs2f(wv[2]), a2);
      a3 = fmaf(h0.w, bs2f(wv[3]), a3);
      a0 = fmaf(h1.x, bs2f(wv[4]), a0);
      a1 = fmaf(h1.y, bs2f(wv[5]), a1);
      a2 = fmaf(h1.z, bs2f(wv[6]), a2);
      a3 = fmaf(h1.w, bs2f(wv[7]), a3);
    }
    v = (a0 + a1) + (a2 + a3);
  }
  hout[gid] = fmaxf(v, 0.f);
}

// ---------- naive head ----------
__global__ __launch_bounds__(256) void final_naive_k(
    const float* __restrict__ hs, const float* __restrict__ Wo,
    const float* __restrict__ bo, const float* __restrict__ sv,
    float* __restrict__ out)
{
  int gid = blockIdx.x * 256 + threadIdx.x;  // exactly 8192*10
  int row = gid / 10, o = gid - row * 10;
  float ps = 1.f;
#pragma unroll
  for (int i = 0; i < 12; ++i) ps *= sv[i];
  const float* hr = hs + row * 128;
  const float* wr = Wo + o * 128;
  float a = bo[o];
#pragma unroll 8
  for (int d = 0; d < 128; ++d) a = fmaf(hr[d], wr[d], a);
  out[gid] = a * ps;
}

extern "C" void kernel_launch(void* const* d_in, const int* in_sizes, int n_in,
                              void* d_out, int out_size, void* d_ws, size_t ws_size,
                              hipStream_t stream)
{
  float* out = (float*)d_out;

  static const int EXP[19] = {2097152, 98304, 12, 288, 32, 9216, 32, 9216, 32,
                              32, 32, 32, 32, 32, 32, 49152, 384, 1280, 10};
  int bad = -1;
  if (n_in != 19) bad = 100;
  else
    for (int i = 0; i < 19; ++i)
      if (in_sizes[i] != EXP[i]) { bad = i; break; }
  if (bad >= 0) {
    fill_k<<<(out_size + 255) / 256, 256, 0, stream>>>(out, 1000.f + 10.f * bad, out_size);
    return;
  }
  const size_t NEED = 73761792;
  if (ws_size < NEED) {
    fill_k<<<(out_size + 255) / 256, 256, 0, stream>>>(
        out, 3000.f + (float)(ws_size >> 20), out_size);
    return;
  }

  const float* x    = (const float*)d_in[0];
  const float* traj = (const float*)d_in[1];
  const float* sv   = (const float*)d_in[2];
  const float* c1w  = (const float*)d_in[3];
  const float* c1b  = (const float*)d_in[4];
  const float* c2w  = (const float*)d_in[5];
  const float* c3w  = (const float*)d_in[7];
  const float* g1   = (const float*)d_in[9];
  const float* bt1  = (const float*)d_in[10];
  const float* g2   = (const float*)d_in[11];
  const float* bt2  = (const float*)d_in[12];
  const float* g3   = (const float*)d_in[13];
  const float* bt3  = (const float*)d_in[14];
  const float* We   = (const float*)d_in[15];
  const float* be   = (const float*)d_in[16];
  const float* Wo   = (const float*)d_in[17];
  const float* bo   = (const float*)d_in[18];

  char* w = (char*)d_ws;
  bf16*  pooled1  = (bf16*)(w + 0);          // NHWC bf16, 29,491,200 B
  bf16*  conv2out = (bf16*)(w + 29491200);   // NHWC bf16, 22,151,168 B
  bf16*  pooled2  = (bf16*)(w + 51642368);   // NHWC bf16, 4,718,592 B
  bf16*  Web      = (bf16*)(w + 56360960);   // 98,304 B
  float* conv3out = (float*)(w + 61079552);  // NHWC f32, 4,194,304 B
  float* hsA      = (float*)(w + 65273856);  // 4,194,304 B
  float* hsB      = (float*)(w + 69468160);  // 4,194,304 B
  float* bnp1     = (float*)(w + 73662464);
  float* bnp2     = (float*)(w + 73662720);
  float* bnp3     = (float*)(w + 73662976);
  float* Mred     = (float*)(w + 73663232);  // 54 f32 (256 B)
  bf16*  WebT     = (bf16*)(w + 73663488);   // 98,304 B -> end 73,761,792
  // short-lived aliases (lifetimes verified disjoint):
  float* partial1 = (float*)conv2out;        // 512*64 f32; dead before conv2 mfma writes
  float* partial2 = (float*)pooled2;         // 1024*64 f32; dead before conv2_apply writes
  float* partial3 = (float*)hsA;             // 256*64 f32; dead before conv3_apply writes
  bf16*  w2b      = (bf16*)hsB;              // read until conv2 mfma; hsB written at moe step 0
  bf16*  w3b      = w2b + 9216;              // read until conv3 mfma

  prep_w_k<<<456, 256, 0, stream>>>(c2w, c3w, We, w2b, w3b, Web, WebT);
  conv1_acc_k<<<512, 256, 0, stream>>>(x, partial1);
  reduce54_k<<<54, 256, 0, stream>>>(partial1, Mred);
  bn1_final_k<<<1, 64, 0, stream>>>(Mred, c1w, c1b, g1, bt1, bnp1);
  conv1_apply_k<<<2048, 256, 0, stream>>>(x, c1w, c1b, bnp1, pooled1);
  conv_mfma_k<15, 13, 169, true><<<1024, 256, 0, stream>>>(pooled1, w2b, conv2out,
                                                           partial2, 21632);
  bn_reduce_partial_k<<<32, 256, 0, stream>>>(partial2, g2, bt2, bnp2, 1024,
                                              1.f / (2048.f * 169.f));
  conv2_apply_k<<<1152, 256, 0, stream>>>(conv2out, bnp2, pooled2);
  conv_mfma_k<6, 4, 16, false><<<256, 256, 0, stream>>>(pooled2, w3b, conv3out,
                                                        partial3, 2048);
  bn_reduce_partial_k<<<32, 256, 0, stream>>>(partial3, g3, bt3, bnp3, 256,
                                              1.f / (2048.f * 16.f));
  conv3_apply_k<<<1024, 256, 0, stream>>>(conv3out, bnp3, hsA);
  moe_naive_k<<<4096, 256, 0, stream>>>(hsA, hsB, traj, WebT, be, 0);
  moe_naive_k<<<4096, 256, 0, stream>>>(hsB, hsA, traj, WebT, be, 1);
  moe_naive_k<<<4096, 256, 0, stream>>>(hsA, hsB, traj, WebT, be, 2);
  final_naive_k<<<320, 256, 0, stream>>>(hsB, Wo, bo, sv, out);
}

// Round 9
// 149.028 us; speedup vs baseline: 1.6177x; 1.6177x over previous
//
#include <hip/hip_runtime.h>
#include <hip/hip_bf16.h>

#define EPSV 1e-5f
typedef __hip_bfloat16 bf16;
typedef __attribute__((ext_vector_type(8))) short v8s;
typedef __attribute__((ext_vector_type(4))) float v4f;
__device__ __forceinline__ float b2f(bf16 v) { return __bfloat162float(v); }
__device__ __forceinline__ bf16 f2b(float v) { return __float2bfloat16(v); }
__device__ __forceinline__ float bs2f(short s) {
  return __uint_as_float(((unsigned)(unsigned short)s) << 16);
}
__device__ __forceinline__ short f2bs(float v) {
  bf16 b = __float2bfloat16(v);
  return *(short*)&b;
}

__global__ __launch_bounds__(256) void fill_k(float* __restrict__ out, float val, int n)
{
  int i = blockIdx.x * 256 + threadIdx.x;
  if (i < n) out[i] = val;
}

// ---------- prep: pack conv2/conv3 weights [(s)*32+ic][oc] bf16; We->bf16; zero cnt ----------
__global__ __launch_bounds__(256) void prep_w_k(
    const float* __restrict__ w2, const float* __restrict__ w3,
    const float* __restrict__ We,
    bf16* __restrict__ w2b, bf16* __restrict__ w3b,
    bf16* __restrict__ Web, int* __restrict__ cnt)
{
  int i = blockIdx.x * 256 + threadIdx.x;
  if (i < 16) cnt[i] = 0;
  if (i < 9216) {
    int oc = i & 31, k = i >> 5, s = k >> 5, ic = k & 31;
    w2b[i] = f2b(w2[oc * 288 + ic * 9 + s]);
  } else if (i < 18432) {
    int j = i - 9216;
    int oc = j & 31, k = j >> 5, s = k >> 5, ic = k & 31;
    w3b[j] = f2b(w3[oc * 288 + ic * 9 + s]);
  } else if (i < 18432 + 49152) {
    int j = i - 18432;
    Web[j] = f2b(We[j]);
  }
}

// ---------- per-(step,expert) row compaction ----------
__global__ __launch_bounds__(256) void compact_k(
    const float* __restrict__ traj, int* __restrict__ cnt, int* __restrict__ lists)
{
  int step = blockIdx.y;
  int row = blockIdx.x * 256 + threadIdx.x;   // 32 blocks x 256 = 8192
  __shared__ int lcnt[3], lbase[3];
  if (threadIdx.x < 3) lcnt[threadIdx.x] = 0;
  __syncthreads();
  float4 tv = ((const float4*)traj)[step * 8192 + row];
  int e = 0; float bv = tv.x;
  if (tv.y > bv) { bv = tv.y; e = 1; }
  if (tv.z > bv) { bv = tv.z; e = 2; }
  if (tv.w > bv) { bv = tv.w; e = 3; }
  int my = 0;
  if (e < 3) my = atomicAdd(&lcnt[e], 1);
  __syncthreads();
  if (threadIdx.x < 3)
    lbase[threadIdx.x] = atomicAdd(&cnt[step * 3 + threadIdx.x], lcnt[threadIdx.x]);
  __syncthreads();
  if (e < 3) lists[(step * 3 + e) * 8192 + lbase[e] + my] = row;
}

// ---------- MoE step via MFMA over compacted rows, in-place hs ----------
__global__ __launch_bounds__(256) void moe_mfma_k(
    float* __restrict__ hs, const bf16* __restrict__ Web,
    const float* __restrict__ be, const int* __restrict__ lists,
    const int* __restrict__ cnt, int step)
{
  int e = blockIdx.y;
  int count = cnt[step * 3 + e];
  if (count == 0) return;
  int t = threadIdx.x, lane = t & 63, wv = t >> 6;
  int m = lane & 15, kg = lane >> 4;
  const short* wbs = (const short*)(Web + e * 16384);
  const int* lp = lists + (step * 3 + e) * 8192;
  float bias[8];
#pragma unroll
  for (int ob = 0; ob < 8; ++ob) bias[ob] = be[e * 128 + ob * 16 + m];
  int ntiles = (count + 15) >> 4;
  for (int tile = blockIdx.x * 4 + wv; tile < ntiles; tile += gridDim.x * 4) {
    int ra = tile * 16 + m;
    int rowA = lp[ra < count ? ra : count - 1];
    const float* hrow = hs + rowA * 128;
    v8s afr[4];
#pragma unroll
    for (int kk = 0; kk < 4; ++kk) {
      float4 h0 = *(const float4*)(hrow + kk * 32 + kg * 8);
      float4 h1 = *(const float4*)(hrow + kk * 32 + kg * 8 + 4);
      afr[kk][0] = f2bs(h0.x); afr[kk][1] = f2bs(h0.y);
      afr[kk][2] = f2bs(h0.z); afr[kk][3] = f2bs(h0.w);
      afr[kk][4] = f2bs(h1.x); afr[kk][5] = f2bs(h1.y);
      afr[kk][6] = f2bs(h1.z); afr[kk][7] = f2bs(h1.w);
    }
    bool wok[4]; int crow[4];
#pragma unroll
    for (int j = 0; j < 4; ++j) {
      int idx = tile * 16 + kg * 4 + j;
      wok[j] = idx < count;
      crow[j] = lp[wok[j] ? idx : 0];
    }
#pragma unroll
    for (int ob = 0; ob < 8; ++ob) {
      v4f acc = {0.f, 0.f, 0.f, 0.f};
#pragma unroll
      for (int kk = 0; kk < 4; ++kk) {
        v8s bfr;
#pragma unroll
        for (int j = 0; j < 8; ++j)
          bfr[j] = wbs[(kk * 32 + kg * 8 + j) * 128 + ob * 16 + m];
        acc = __builtin_amdgcn_mfma_f32_16x16x32_bf16(afr[kk], bfr, acc, 0, 0, 0);
      }
#pragma unroll
      for (int j = 0; j < 4; ++j)
        if (wok[j]) hs[crow[j] * 128 + ob * 16 + m] = fmaxf(acc[j] + bias[ob], 0.f);
    }
  }
}

// ---------- conv1 stats via autocorrelation: 4 images/block -> 54 partials ----------
__global__ __launch_bounds__(256) void conv1_acc_k(
    const float* __restrict__ x, float* __restrict__ partial)
{
  int t = threadIdx.x;
  __shared__ __align__(16) float xs[1024];
  float M[45], S[9];
#pragma unroll
  for (int k = 0; k < 45; ++k) M[k] = 0.f;
#pragma unroll
  for (int k = 0; k < 9; ++k) S[k] = 0.f;
  for (int im = 0; im < 4; ++im) {
    int img = blockIdx.x * 4 + im;
    ((float4*)xs)[t] = ((const float4*)(x + img * 1024))[t];
    __syncthreads();
    for (int p = t; p < 900; p += 256) {
      int y = p / 30, xx = p - y * 30;
      const float* r0 = xs + y * 32 + xx;
      float v[9];
      v[0] = r0[0];  v[1] = r0[1];  v[2] = r0[2];
      v[3] = r0[32]; v[4] = r0[33]; v[5] = r0[34];
      v[6] = r0[64]; v[7] = r0[65]; v[8] = r0[66];
      int idx = 0;
#pragma unroll
      for (int i = 0; i < 9; ++i) {
        S[i] += v[i];
#pragma unroll
        for (int j = i; j < 9; ++j) M[idx++] = fmaf(v[i], v[j], M[idx]);
      }
    }
    __syncthreads();
  }
  float a[54];
#pragma unroll
  for (int k = 0; k < 45; ++k) a[k] = M[k];
#pragma unroll
  for (int k = 0; k < 9; ++k) a[45 + k] = S[k];
#pragma unroll
  for (int k = 0; k < 54; ++k) {
#pragma unroll
    for (int off = 32; off; off >>= 1) a[k] += __shfl_down(a[k], off, 64);
  }
  __shared__ float red[4][54];
  int wv = t >> 6, lane = t & 63;
  if (lane == 0) {
#pragma unroll
    for (int k = 0; k < 54; ++k) red[wv][k] = a[k];
  }
  __syncthreads();
  if (t < 54)
    partial[blockIdx.x * 64 + t] = red[0][t] + red[1][t] + red[2][t] + red[3][t];
}

// ---------- reduce 512 blocks of 54 partials ----------
__global__ __launch_bounds__(256) void reduce54_k(
    const float* __restrict__ partial, float* __restrict__ Mred)
{
  int c = blockIdx.x, t = threadIdx.x;
  float s = 0.f;
  for (int i = t; i < 512; i += 256) s += partial[i * 64 + c];
#pragma unroll
  for (int off = 32; off; off >>= 1) s += __shfl_down(s, off, 64);
  __shared__ float rs[4];
  int wv = t >> 6, lane = t & 63;
  if (lane == 0) rs[wv] = s;
  __syncthreads();
  if (t == 0) Mred[c] = rs[0] + rs[1] + rs[2] + rs[3];
}

// ---------- conv1 BN params from autocorrelation ----------
__global__ void bn1_final_k(
    const float* __restrict__ Mred, const float* __restrict__ w1,
    const float* __restrict__ b1, const float* __restrict__ g,
    const float* __restrict__ bt, float* __restrict__ bnp)
{
  __shared__ float Ms[54];
  int t = threadIdx.x;
  if (t < 54) Ms[t] = Mred[t];
  __syncthreads();
  if (t < 32) {
    float w[9];
#pragma unroll
    for (int j = 0; j < 9; ++j) w[j] = w1[t * 9 + j];
    float b = b1[t];
    float wS = 0.f;
#pragma unroll
    for (int i = 0; i < 9; ++i) wS = fmaf(w[i], Ms[45 + i], wS);
    float wMw = 0.f;
    int idx = 0;
#pragma unroll
    for (int i = 0; i < 9; ++i)
#pragma unroll
      for (int j = i; j < 9; ++j) {
        float coef = (i == j) ? 1.f : 2.f;
        wMw = fmaf(coef * w[i] * w[j], Ms[idx++], wMw);
      }
    const float Np = 2048.f * 900.f;
    float mean = (wS + Np * b) / Np;
    float sumsq = wMw + 2.f * b * wS + Np * b * b;
    float var = sumsq / Np - mean * mean;
    float sc = g[t] / sqrtf(var + EPSV);
    bnp[2 * t] = sc;
    bnp[2 * t + 1] = bt[t] - mean * sc;
  }
}

// ---------- conv1 apply: block per image, float2 patch loads, regs for weights ----------
__global__ __launch_bounds__(256) void conv1_apply_k(
    const float* __restrict__ x, const float* __restrict__ w1,
    const float* __restrict__ b1, const float* __restrict__ bnp,
    bf16* __restrict__ pooled1)
{
  int img = blockIdx.x, t = threadIdx.x;
  __shared__ __align__(16) float xs[1024];
  ((float4*)xs)[t] = ((const float4*)(x + img * 1024))[t];
  __syncthreads();
  int c = t & 31;
  float w[9];
#pragma unroll
  for (int j = 0; j < 9; ++j) w[j] = w1[c * 9 + j];
  float bias = b1[c], sc = bnp[2 * c], sh = bnp[2 * c + 1];
  bf16* outp = pooled1 + img * 7200;
  for (int idx = t; idx < 7200; idx += 256) {
    int pp = idx >> 5;
    int py = pp / 15, px = pp - py * 15;
    int y0 = 2 * py, x0 = 2 * px;
    float rv[4][4];
#pragma unroll
    for (int rr = 0; rr < 4; ++rr) {
      float2 lo = *(const float2*)(xs + (y0 + rr) * 32 + x0);
      float2 hi = *(const float2*)(xs + (y0 + rr) * 32 + x0 + 2);
      rv[rr][0] = lo.x; rv[rr][1] = lo.y; rv[rr][2] = hi.x; rv[rr][3] = hi.y;
    }
    float r = 0.f;
#pragma unroll
    for (int i = 0; i < 2; ++i)
#pragma unroll
      for (int j = 0; j < 2; ++j) {
        float v = bias;
        v = fmaf(rv[i][j],     w[0], v); v = fmaf(rv[i][j + 1],     w[1], v); v = fmaf(rv[i][j + 2],     w[2], v);
        v = fmaf(rv[i + 1][j], w[3], v); v = fmaf(rv[i + 1][j + 1], w[4], v); v = fmaf(rv[i + 1][j + 2], w[5], v);
        v = fmaf(rv[i + 2][j], w[6], v); v = fmaf(rv[i + 2][j + 1], w[7], v); v = fmaf(rv[i + 2][j + 2], w[8], v);
        r += fmaxf(fmaf(v, sc, sh), 0.f);
      }
    outp[idx] = f2b(r * 0.25f);
  }
}

// ---------- generic partial reduce -> scale/shift (conv2/conv3 stats) ----------
__global__ __launch_bounds__(256) void bn_reduce_partial_k(
    const float* __restrict__ partial, const float* __restrict__ g,
    const float* __restrict__ bt, float* __restrict__ bnp,
    int nimg, float invn)
{
  int c = blockIdx.x, t = threadIdx.x;
  float s = 0.f, ss = 0.f;
  for (int i = t; i < nimg; i += 256) {
    s += partial[i * 64 + c * 2];
    ss += partial[i * 64 + c * 2 + 1];
  }
#pragma unroll
  for (int off = 32; off; off >>= 1) { s += __shfl_down(s, off, 64); ss += __shfl_down(ss, off, 64); }
  __shared__ float rs[4], rss[4];
  int wv = t >> 6, lane = t & 63;
  if (lane == 0) { rs[wv] = s; rss[wv] = ss; }
  __syncthreads();
  if (t == 0) {
    s = rs[0] + rs[1] + rs[2] + rs[3];
    ss = rss[0] + rss[1] + rss[2] + rss[3];
    float mean = s * invn;
    float var = ss * invn - mean * mean;
    float sc = g[c] / sqrtf(var + EPSV);
    bnp[2 * c] = sc;
    bnp[2 * c + 1] = bt[c] - mean * sc;
  }
}

// ---------- implicit-GEMM conv via MFMA, NHWC in/out, fused BN-stats partials ----------
template <int IN_W, int OUT_W, int OUT_PIX, bool OUT_BF16>
__global__ __launch_bounds__(256) void conv_mfma_k(
    const bf16* __restrict__ in, const bf16* __restrict__ wb,
    void* __restrict__ outv, float* __restrict__ partial, int ntiles)
{
  constexpr int IN_PIX = IN_W * IN_W;
  int t = threadIdx.x, lane = t & 63;
  int m = lane & 15, kg = lane >> 4;
  const short* wbs = (const short*)wb;
  v8s bfr[9][2];
#pragma unroll
  for (int s = 0; s < 9; ++s)
#pragma unroll
    for (int ob = 0; ob < 2; ++ob)
#pragma unroll
      for (int j = 0; j < 8; ++j)
        bfr[s][ob][j] = wbs[(s * 32 + kg * 8 + j) * 32 + ob * 16 + m];

  float rs0 = 0.f, rss0 = 0.f, rs1 = 0.f, rss1 = 0.f;
  int gwave = blockIdx.x * 4 + (t >> 6);
  int nw = gridDim.x * 4;
  for (int tile = gwave; tile < ntiles; tile += nw) {
    unsigned p = tile * 16 + m;
    unsigned img = p / OUT_PIX, pix = p - img * OUT_PIX;
    unsigned y = pix / OUT_W, x = pix - y * OUT_W;
    const bf16* ap = in + img * (IN_PIX * 32) + (y * IN_W + x) * 32 + kg * 8;
    v4f acc0 = {0.f, 0.f, 0.f, 0.f}, acc1 = {0.f, 0.f, 0.f, 0.f};
#pragma unroll
    for (int ky = 0; ky < 3; ++ky)
#pragma unroll
      for (int kx = 0; kx < 3; ++kx) {
        v8s a = *(const v8s*)(ap + (ky * IN_W + kx) * 32);
        acc0 = __builtin_amdgcn_mfma_f32_16x16x32_bf16(a, bfr[ky * 3 + kx][0], acc0, 0, 0, 0);
        acc1 = __builtin_amdgcn_mfma_f32_16x16x32_bf16(a, bfr[ky * 3 + kx][1], acc1, 0, 0, 0);
      }
#pragma unroll
    for (int j = 0; j < 4; ++j) {
      rs0 += acc0[j]; rss0 = fmaf(acc0[j], acc0[j], rss0);
      rs1 += acc1[j]; rss1 = fmaf(acc1[j], acc1[j], rss1);
      unsigned pr = tile * 16 + kg * 4 + j;
      unsigned img2 = pr / OUT_PIX, pix2 = pr - img2 * OUT_PIX;
      unsigned base = (img2 * OUT_PIX + pix2) * 32;
      if (OUT_BF16) {
        bf16* o = (bf16*)outv;
        o[base + m] = f2b(acc0[j]);
        o[base + 16 + m] = f2b(acc1[j]);
      } else {
        float* o = (float*)outv;
        o[base + m] = acc0[j];
        o[base + 16 + m] = acc1[j];
      }
    }
  }
  rs0 += __shfl_xor(rs0, 16, 64);  rs0 += __shfl_xor(rs0, 32, 64);
  rss0 += __shfl_xor(rss0, 16, 64); rss0 += __shfl_xor(rss0, 32, 64);
  rs1 += __shfl_xor(rs1, 16, 64);  rs1 += __shfl_xor(rs1, 32, 64);
  rss1 += __shfl_xor(rss1, 16, 64); rss1 += __shfl_xor(rss1, 32, 64);
  __shared__ float red[4][32][2];
  int wv = t >> 6;
  if (lane < 16) {
    red[wv][lane][0] = rs0;      red[wv][lane][1] = rss0;
    red[wv][16 + lane][0] = rs1; red[wv][16 + lane][1] = rss1;
  }
  __syncthreads();
  if (t < 64) {
    int cc = t >> 1, j = t & 1;
    partial[blockIdx.x * 64 + t] = red[0][cc][j] + red[1][cc][j] + red[2][cc][j] + red[3][cc][j];
  }
}

// ---------- conv2 apply: NHWC vectorized BN+ReLU+pool 13->6 -> NHWC bf16 ----------
__global__ __launch_bounds__(256) void conv2_apply_k(
    const bf16* __restrict__ in, const float* __restrict__ bnp,
    bf16* __restrict__ out)
{
  int idx = blockIdx.x * 256 + threadIdx.x;  // exactly 2048*36*4
  int img = idx / 144, r = idx - img * 144;
  int pp = r >> 2, c8 = r & 3;
  int py = pp / 6, px = pp - py * 6;
  int ip0 = (2 * py) * 13 + 2 * px;
  const bf16* bp = in + (img * 169 + ip0) * 32 + c8 * 8;
  v8s a = *(const v8s*)bp;
  v8s b = *(const v8s*)(bp + 32);
  v8s cc = *(const v8s*)(bp + 13 * 32);
  v8s d = *(const v8s*)(bp + 14 * 32);
  const float* bn = bnp + c8 * 16;
  union { v8s v; short s[8]; bf16 h[8]; } res;
#pragma unroll
  for (int k = 0; k < 8; ++k) {
    float sc = bn[2 * k], sh = bn[2 * k + 1];
    float v = fmaxf(fmaf(bs2f(a[k]), sc, sh), 0.f) + fmaxf(fmaf(bs2f(b[k]), sc, sh), 0.f)
            + fmaxf(fmaf(bs2f(cc[k]), sc, sh), 0.f) + fmaxf(fmaf(bs2f(d[k]), sc, sh), 0.f);
    res.h[k] = f2b(v * 0.25f);
  }
  *(v8s*)(out + (img * 36 + pp) * 32 + c8 * 8) = res.v;
}

// ---------- conv3 apply + pool + broadcast to 4 beams (NHWC fp32 in) ----------
__global__ __launch_bounds__(256) void conv3_apply_k(
    const float* __restrict__ in, const float* __restrict__ bnp,
    float* __restrict__ hs)
{
  int idx = blockIdx.x * 256 + threadIdx.x;  // exactly 2048*128
  int img = idx >> 7, r = idx & 127;
  int c = r >> 2, q = r & 3;
  int py = q >> 1, px = q & 1;
  int p0 = py * 8 + px * 2;
  const float* bp = in + img * 512 + c;
  float sc = bnp[2 * c], sh = bnp[2 * c + 1];
  float v = (fmaxf(fmaf(bp[p0 * 32], sc, sh), 0.f)
           + fmaxf(fmaf(bp[(p0 + 1) * 32], sc, sh), 0.f)
           + fmaxf(fmaf(bp[(p0 + 4) * 32], sc, sh), 0.f)
           + fmaxf(fmaf(bp[(p0 + 5) * 32], sc, sh), 0.f)) * 0.25f;
  float* hb = hs + img * 512 + r;
  hb[0] = v; hb[128] = v; hb[256] = v; hb[384] = v;
}

// ---------- naive head ----------
__global__ __launch_bounds__(256) void final_naive_k(
    const float* __restrict__ hs, const float* __restrict__ Wo,
    const float* __restrict__ bo, const float* __restrict__ sv,
    float* __restrict__ out)
{
  int gid = blockIdx.x * 256 + threadIdx.x;  // exactly 8192*10
  int row = gid / 10, o = gid - row * 10;
  float ps = 1.f;
#pragma unroll
  for (int i = 0; i < 12; ++i) ps *= sv[i];
  const float* hr = hs + row * 128;
  const float* wr = Wo + o * 128;
  float a = bo[o];
#pragma unroll 8
  for (int d = 0; d < 128; ++d) a = fmaf(hr[d], wr[d], a);
  out[gid] = a * ps;
}

extern "C" void kernel_launch(void* const* d_in, const int* in_sizes, int n_in,
                              void* d_out, int out_size, void* d_ws, size_t ws_size,
                              hipStream_t stream)
{
  float* out = (float*)d_out;

  static const int EXP[19] = {2097152, 98304, 12, 288, 32, 9216, 32, 9216, 32,
                              32, 32, 32, 32, 32, 32, 49152, 384, 1280, 10};
  int bad = -1;
  if (n_in != 19) bad = 100;
  else
    for (int i = 0; i < 19; ++i)
      if (in_sizes[i] != EXP[i]) { bad = i; break; }
  if (bad >= 0) {
    fill_k<<<(out_size + 255) / 256, 256, 0, stream>>>(out, 1000.f + 10.f * bad, out_size);
    return;
  }
  const size_t NEED = 73958656;
  if (ws_size < NEED) {
    fill_k<<<(out_size + 255) / 256, 256, 0, stream>>>(
        out, 3000.f + (float)(ws_size >> 20), out_size);
    return;
  }

  const float* x    = (const float*)d_in[0];
  const float* traj = (const float*)d_in[1];
  const float* sv   = (const float*)d_in[2];
  const float* c1w  = (const float*)d_in[3];
  const float* c1b  = (const float*)d_in[4];
  const float* c2w  = (const float*)d_in[5];
  const float* c3w  = (const float*)d_in[7];
  const float* g1   = (const float*)d_in[9];
  const float* bt1  = (const float*)d_in[10];
  const float* g2   = (const float*)d_in[11];
  const float* bt2  = (const float*)d_in[12];
  const float* g3   = (const float*)d_in[13];
  const float* bt3  = (const float*)d_in[14];
  const float* We   = (const float*)d_in[15];
  const float* be   = (const float*)d_in[16];
  const float* Wo   = (const float*)d_in[17];
  const float* bo   = (const float*)d_in[18];

  char* w = (char*)d_ws;
  bf16*  pooled1  = (bf16*)(w + 0);          // NHWC bf16, 29,491,200 B
  bf16*  conv2out = (bf16*)(w + 29491200);   // NHWC bf16, 22,151,168 B
  bf16*  pooled2  = (bf16*)(w + 51642368);   // NHWC bf16, 4,718,592 B
  bf16*  Web      = (bf16*)(w + 56360960);   // 98,304 B
  float* conv3out = (float*)(w + 61079552);  // NHWC f32, 4,194,304 B
  float* hsA      = (float*)(w + 65273856);  // 4,194,304 B
  float* hsB      = (float*)(w + 69468160);  // 4,194,304 B (now only weight staging)
  float* bnp1     = (float*)(w + 73662464);
  float* bnp2     = (float*)(w + 73662720);
  float* bnp3     = (float*)(w + 73662976);
  float* Mred     = (float*)(w + 73663232);  // 256 B
  int*   cnt      = (int*)(w + 73663488);    // 64 B (16 ints)
  int*   lists    = (int*)(w + 73663744);    // 3*3*8192*4 = 294,912 B -> end 73,958,656
  // short-lived aliases (lifetimes verified disjoint):
  float* partial1 = (float*)conv2out;        // dead before conv2 mfma writes
  float* partial2 = (float*)pooled2;         // dead before conv2_apply writes
  float* partial3 = (float*)hsA;             // dead before conv3_apply writes
  bf16*  w2b      = (bf16*)hsB;              // hsB otherwise unused now
  bf16*  w3b      = w2b + 9216;

  prep_w_k<<<264, 256, 0, stream>>>(c2w, c3w, We, w2b, w3b, Web, cnt);
  compact_k<<<dim3(32, 3), 256, 0, stream>>>(traj, cnt, lists);
  conv1_acc_k<<<512, 256, 0, stream>>>(x, partial1);
  reduce54_k<<<54, 256, 0, stream>>>(partial1, Mred);
  bn1_final_k<<<1, 64, 0, stream>>>(Mred, c1w, c1b, g1, bt1, bnp1);
  conv1_apply_k<<<2048, 256, 0, stream>>>(x, c1w, c1b, bnp1, pooled1);
  conv_mfma_k<15, 13, 169, true><<<1024, 256, 0, stream>>>(pooled1, w2b, conv2out,
                                                           partial2, 21632);
  bn_reduce_partial_k<<<32, 256, 0, stream>>>(partial2, g2, bt2, bnp2, 1024,
                                              1.f / (2048.f * 169.f));
  conv2_apply_k<<<1152, 256, 0, stream>>>(conv2out, bnp2, pooled2);
  conv_mfma_k<6, 4, 16, false><<<256, 256, 0, stream>>>(pooled2, w3b, conv3out,
                                                        partial3, 2048);
  bn_reduce_partial_k<<<32, 256, 0, stream>>>(partial3, g3, bt3, bnp3, 256,
                                              1.f / (2048.f * 16.f));
  conv3_apply_k<<<1024, 256, 0, stream>>>(conv3out, bnp3, hsA);
  moe_mfma_k<<<dim3(128, 3), 256, 0, stream>>>(hsA, Web, be, lists, cnt, 0);
  moe_mfma_k<<<dim3(128, 3), 256, 0, stream>>>(hsA, Web, be, lists, cnt, 1);
  moe_mfma_k<<<dim3(128, 3), 256, 0, stream>>>(hsA, Web, be, lists, cnt, 2);
  final_naive_k<<<320, 256, 0, stream>>>(hsA, Wo, bo, sv, out);
}